// Round 1
// baseline (443.081 us; speedup 1.0000x reference)
//
#include <hip/hip_runtime.h>
#include <hip/hip_bf16.h>

#define N_NODES 65536
#define N_EDGES 1048576
#define F_IN    128
#define HEADS   4
#define HID     64
#define NHID    256   // HEADS*HID
#define OUTC    512   // xs(256) ++ xd(256) per node row

// ---------------------------------------------------------------- BN stats
__global__ __launch_bounds__(256) void k_bn_stats(const float* __restrict__ x,
                                                  float* __restrict__ sums) {
    const int t = threadIdx.x;
    const int lane = t & 63;
    const int w = t >> 6;
    const int wid = blockIdx.x * 4 + w;            // 0..1023 global wave id
    float s0 = 0.f, s1 = 0.f, q0 = 0.f, q1 = 0.f;
    for (int i = 0; i < 64; ++i) {
        int r = wid + i * 1024;
        float2 v = *(const float2*)(x + (size_t)r * F_IN + lane * 2);
        s0 += v.x; q0 += v.x * v.x;
        s1 += v.y; q1 += v.y * v.y;
    }
    __shared__ float sh[4][128];
    sh[w][lane * 2] = s0; sh[w][lane * 2 + 1] = s1;
    __syncthreads();
    if (t < 128) atomicAdd(&sums[t], sh[0][t] + sh[1][t] + sh[2][t] + sh[3][t]);
    __syncthreads();
    sh[w][lane * 2] = q0; sh[w][lane * 2 + 1] = q1;
    __syncthreads();
    if (t < 128) atomicAdd(&sums[128 + t], sh[0][t] + sh[1][t] + sh[2][t] + sh[3][t]);
}

__global__ void k_bn_finalize(const float* __restrict__ sums,
                              const float* __restrict__ gamma,
                              const float* __restrict__ beta,
                              float* __restrict__ scale,
                              float* __restrict__ shift) {
    int t = threadIdx.x;  // 128 threads
    float mean = sums[t] * (1.0f / N_NODES);
    float var  = sums[128 + t] * (1.0f / N_NODES) - mean * mean;
    float sc = gamma[t] * rsqrtf(var + 1e-5f);
    scale[t] = sc;
    shift[t] = beta[t] - mean * sc;
}

// Fold BN affine into weights: W'[o][k] = W[o][k]*scale[k]; b'[o] = b[o] + sum_k shift[k]*W[o][k]
__global__ __launch_bounds__(256) void k_prep_w(const float* __restrict__ w_l,
                                                const float* __restrict__ b_l,
                                                const float* __restrict__ w_r,
                                                const float* __restrict__ b_r,
                                                const float* __restrict__ scale,
                                                const float* __restrict__ shift,
                                                float* __restrict__ Wp,
                                                float* __restrict__ bp) {
    const int t = threadIdx.x;
    const int lane = t & 63;
    const int o = blockIdx.x * 4 + (t >> 6);       // 0..511
    const float* wrow = (o < NHID) ? (w_l + (size_t)o * F_IN)
                                   : (w_r + (size_t)(o - NHID) * F_IN);
    float bo = (o < NHID) ? b_l[o] : b_r[o - NHID];
    float2 wv = *(const float2*)(wrow + lane * 2);
    float sc0 = scale[lane * 2], sc1 = scale[lane * 2 + 1];
    Wp[(size_t)o * F_IN + lane * 2]     = wv.x * sc0;
    Wp[(size_t)o * F_IN + lane * 2 + 1] = wv.y * sc1;
    float part = shift[lane * 2] * wv.x + shift[lane * 2 + 1] * wv.y;
    #pragma unroll
    for (int m = 1; m < 64; m <<= 1) part += __shfl_xor(part, m, 64);
    if (lane == 0) bp[o] = bo + part;
}

// ---------------------------------------------------------------- GEMM (fp32)
// xsd[n][0:256] = xs, xsd[n][256:512] = xd
__global__ __launch_bounds__(256) void k_gemm(const float* __restrict__ x,
                                              const float* __restrict__ Wp,
                                              const float* __restrict__ bp,
                                              float* __restrict__ xsd) {
    __shared__ __align__(16) float As[32][68];  // k-major, pad 68 -> 4-way write conflict only
    __shared__ __align__(16) float Bs[32][68];
    const int t = threadIdx.x;
    const int m0 = blockIdx.y * 64;
    const int n0 = blockIdx.x * 64;
    const int tx = t & 15, ty = t >> 4;
    float acc[4][4] = {};
    for (int kt = 0; kt < 4; ++kt) {
        const int k0 = kt * 32;
        #pragma unroll
        for (int q = 0; q < 2; ++q) {
            int f = t + q * 256;          // 0..511 float4 slots
            int row = f >> 3;
            int kq = (f & 7) << 2;
            float4 av = *(const float4*)(x  + (size_t)(m0 + row) * F_IN + k0 + kq);
            float4 bv = *(const float4*)(Wp + (size_t)(n0 + row) * F_IN + k0 + kq);
            As[kq + 0][row] = av.x; As[kq + 1][row] = av.y;
            As[kq + 2][row] = av.z; As[kq + 3][row] = av.w;
            Bs[kq + 0][row] = bv.x; Bs[kq + 1][row] = bv.y;
            Bs[kq + 2][row] = bv.z; Bs[kq + 3][row] = bv.w;
        }
        __syncthreads();
        #pragma unroll
        for (int kk = 0; kk < 32; ++kk) {
            float4 a4 = *(const float4*)&As[kk][ty * 4];
            float4 b4 = *(const float4*)&Bs[kk][tx * 4];
            float a[4] = {a4.x, a4.y, a4.z, a4.w};
            float b[4] = {b4.x, b4.y, b4.z, b4.w};
            #pragma unroll
            for (int i = 0; i < 4; ++i)
                #pragma unroll
                for (int j = 0; j < 4; ++j)
                    acc[i][j] = fmaf(a[i], b[j], acc[i][j]);
        }
        __syncthreads();
    }
    float4 bb = *(const float4*)(bp + n0 + tx * 4);
    float bcol[4] = {bb.x, bb.y, bb.z, bb.w};
    #pragma unroll
    for (int i = 0; i < 4; ++i) {
        float4 o;
        o.x = acc[i][0] + bcol[0]; o.y = acc[i][1] + bcol[1];
        o.z = acc[i][2] + bcol[2]; o.w = acc[i][3] + bcol[3];
        *(float4*)(xsd + (size_t)(m0 + ty * 4 + i) * OUTC + n0 + tx * 4) = o;
    }
}

// ---------------------------------------------------------------- CSR build
__global__ __launch_bounds__(256) void k_hist(const int* __restrict__ ei,
                                              int* __restrict__ counts) {
    int e = blockIdx.x * 256 + threadIdx.x;
    atomicAdd(&counts[ei[N_EDGES + e]], 1);
}

__global__ __launch_bounds__(256) void k_scan1(const int* __restrict__ counts,
                                               int* __restrict__ row_start,
                                               int* __restrict__ blocksums) {
    __shared__ int sh[256];
    int t = threadIdx.x;
    int i = blockIdx.x * 256 + t;
    int v = counts[i];
    sh[t] = v;
    __syncthreads();
    for (int off = 1; off < 256; off <<= 1) {
        int add = (t >= off) ? sh[t - off] : 0;
        __syncthreads();
        sh[t] += add;
        __syncthreads();
    }
    row_start[i] = sh[t] - v;                 // block-local exclusive
    if (t == 255) blocksums[blockIdx.x] = sh[255];
}

__global__ void k_scan2(int* __restrict__ blocksums) {
    __shared__ int sh[256];
    int t = threadIdx.x;
    int v = blocksums[t];
    sh[t] = v;
    __syncthreads();
    for (int off = 1; off < 256; off <<= 1) {
        int add = (t >= off) ? sh[t - off] : 0;
        __syncthreads();
        sh[t] += add;
        __syncthreads();
    }
    blocksums[t] = sh[t] - v;                 // exclusive block offsets
}

__global__ __launch_bounds__(256) void k_scan3(int* __restrict__ row_start,
                                               const int* __restrict__ blocksums,
                                               int* __restrict__ cursor) {
    int i = blockIdx.x * 256 + threadIdx.x;
    int v = row_start[i] + blocksums[blockIdx.x];
    row_start[i] = v;
    cursor[i] = v;
}

__global__ __launch_bounds__(256) void k_scatter(const int* __restrict__ ei,
                                                 int* __restrict__ cursor,
                                                 int* __restrict__ csr) {
    int e = blockIdx.x * 256 + threadIdx.x;
    int s = ei[e];
    int d = ei[N_EDGES + e];
    int pos = atomicAdd(&cursor[d], 1);
    csr[pos] = s;
}

// ---------------------------------------------------------------- aggregation
// one wave per dst node; lane l holds elements [l*4 .. l*4+3] of the 256-wide
// [H=4][C=64] row (head = l>>4). Online softmax over incoming edges + self loop.
__global__ __launch_bounds__(256) void k_aggregate(const float* __restrict__ xsd,
                                                   const int* __restrict__ row_start,
                                                   const int* __restrict__ counts,
                                                   const int* __restrict__ csr,
                                                   const float* __restrict__ att,
                                                   const float* __restrict__ bias,
                                                   float* __restrict__ out) {
    const int t = threadIdx.x;
    const int lane = t & 63;
    const int node = blockIdx.x * 4 + (t >> 6);
    const float4 att4 = *(const float4*)(att + lane * 4);
    const float4 xd4  = *(const float4*)(xsd + (size_t)node * OUTC + NHID + lane * 4);
    float m = -INFINITY, s = 0.f;
    float ax = 0.f, ay = 0.f, az = 0.f, aw = 0.f;
    const int start = row_start[node];
    const int deg = counts[node];
    float4 cur = *(const float4*)(xsd + (size_t)node * OUTC + lane * 4);  // self loop
    for (int i = 0; i <= deg; ++i) {
        float4 nxt = cur;
        if (i < deg) {                         // software prefetch of next edge
            int src = csr[start + i];
            nxt = *(const float4*)(xsd + (size_t)src * OUTC + lane * 4);
        }
        float e0 = cur.x + xd4.x; e0 = (e0 > 0.f) ? e0 : 0.2f * e0;
        float e1 = cur.y + xd4.y; e1 = (e1 > 0.f) ? e1 : 0.2f * e1;
        float e2 = cur.z + xd4.z; e2 = (e2 > 0.f) ? e2 : 0.2f * e2;
        float e3 = cur.w + xd4.w; e3 = (e3 > 0.f) ? e3 : 0.2f * e3;
        float d = e0 * att4.x + e1 * att4.y + e2 * att4.z + e3 * att4.w;
        d += __shfl_xor(d, 1, 64);
        d += __shfl_xor(d, 2, 64);
        d += __shfl_xor(d, 4, 64);
        d += __shfl_xor(d, 8, 64);            // 16-lane head-group logit
        float mn = fmaxf(m, d);
        float f = __expf(m - mn);             // first iter: exp(-inf)=0 zeroes state
        float p = __expf(d - mn);
        s = s * f + p;
        ax = ax * f + p * cur.x;
        ay = ay * f + p * cur.y;
        az = az * f + p * cur.z;
        aw = aw * f + p * cur.w;
        m = mn;
        cur = nxt;
    }
    float inv = 1.0f / s;
    float ox = ax * inv, oy = ay * inv, oz = az * inv, ow = aw * inv;
    ox += __shfl_xor(ox, 16, 64); ox += __shfl_xor(ox, 32, 64);  // head mean
    oy += __shfl_xor(oy, 16, 64); oy += __shfl_xor(oy, 32, 64);
    oz += __shfl_xor(oz, 16, 64); oz += __shfl_xor(oz, 32, 64);
    ow += __shfl_xor(ow, 16, 64); ow += __shfl_xor(ow, 32, 64);
    const float4 b4 = *(const float4*)(bias + (lane & 15) * 4);
    ox = ox * 0.25f + b4.x; oy = oy * 0.25f + b4.y;
    oz = oz * 0.25f + b4.z; ow = ow * 0.25f + b4.w;
    ox = (ox > 0.f) ? ox : expm1f(ox);
    oy = (oy > 0.f) ? oy : expm1f(oy);
    oz = (oz > 0.f) ? oz : expm1f(oz);
    ow = (ow > 0.f) ? ow : expm1f(ow);
    if (lane < 16) {
        float4 o = {ox, oy, oz, ow};
        *(float4*)(out + (size_t)node * HID + lane * 4) = o;
    }
}

// ---------------------------------------------------------------- launch
extern "C" void kernel_launch(void* const* d_in, const int* in_sizes, int n_in,
                              void* d_out, int out_size, void* d_ws, size_t ws_size,
                              hipStream_t stream) {
    const float* x     = (const float*)d_in[0];
    const int*   ei    = (const int*)d_in[1];
    // d_in[2] batch, d_in[3] num_graphs: unused in the computation
    const float* gamma = (const float*)d_in[4];
    const float* beta  = (const float*)d_in[5];
    const float* w_l   = (const float*)d_in[6];
    const float* b_l   = (const float*)d_in[7];
    const float* w_r   = (const float*)d_in[8];
    const float* b_r   = (const float*)d_in[9];
    const float* att   = (const float*)d_in[10];
    const float* bias  = (const float*)d_in[11];
    float* out = (float*)d_out;

    float* ws    = (float*)d_ws;
    float* xsd   = ws;                                   // 65536*512 floats (128 MB)
    float* Wp    = xsd + (size_t)N_NODES * OUTC;         // 512*128
    float* bp    = Wp + 512 * 128;                       // 512
    float* scale = bp + 512;                             // 128
    float* shift = scale + 128;                          // 128
    float* sums  = shift + 128;                          // 256
    int* counts    = (int*)(sums + 256);                 // 65536
    int* row_start = counts + N_NODES;                   // 65536
    int* cursor    = row_start + N_NODES;                // 65536
    int* blocksums = cursor + N_NODES;                   // 256
    int* csr       = blocksums + 256;                    // 1048576

    // zero BN sums + histogram counts (adjacent regions)
    hipMemsetAsync(sums, 0, (256 + N_NODES) * sizeof(float), stream);

    k_bn_stats<<<256, 256, 0, stream>>>(x, sums);
    k_bn_finalize<<<1, 128, 0, stream>>>(sums, gamma, beta, scale, shift);
    k_prep_w<<<128, 256, 0, stream>>>(w_l, b_l, w_r, b_r, scale, shift, Wp, bp);
    k_gemm<<<dim3(8, 1024), 256, 0, stream>>>(x, Wp, bp, xsd);

    k_hist<<<N_EDGES / 256, 256, 0, stream>>>(ei, counts);
    k_scan1<<<256, 256, 0, stream>>>(counts, row_start, blocksums);
    k_scan2<<<1, 256, 0, stream>>>(blocksums);
    k_scan3<<<256, 256, 0, stream>>>(row_start, blocksums, cursor);
    k_scatter<<<N_EDGES / 256, 256, 0, stream>>>(ei, cursor, csr);

    k_aggregate<<<N_NODES / 4, 256, 0, stream>>>(xsd, row_start, counts, csr, att, bias, out);
}

// Round 2
// 398.027 us; speedup vs baseline: 1.1132x; 1.1132x over previous
//
#include <hip/hip_runtime.h>
#include <hip/hip_bf16.h>

#define N_NODES 65536
#define N_EDGES 1048576
#define F_IN    128
#define HEADS   4
#define HID     64
#define NHID    256   // HEADS*HID
#define NEG     0.2f

typedef float fx4 __attribute__((ext_vector_type(4)));

__device__ inline unsigned short f2bf(float f) {
    unsigned u = __float_as_uint(f);
    u += 0x7fff + ((u >> 16) & 1);          // round-to-nearest-even
    return (unsigned short)(u >> 16);
}

// ---------------------------------------------------------------- BN stats
__global__ __launch_bounds__(256) void k_bn_stats(const float* __restrict__ x,
                                                  float* __restrict__ sums) {
    const int t = threadIdx.x;
    const int lane = t & 63;
    const int w = t >> 6;
    const int wid = blockIdx.x * 4 + w;            // 0..1023 global wave id
    float s0 = 0.f, s1 = 0.f, q0 = 0.f, q1 = 0.f;
    for (int i = 0; i < 64; ++i) {
        int r = wid + i * 1024;
        float2 v = *(const float2*)(x + (size_t)r * F_IN + lane * 2);
        s0 += v.x; q0 += v.x * v.x;
        s1 += v.y; q1 += v.y * v.y;
    }
    __shared__ float sh[4][128];
    sh[w][lane * 2] = s0; sh[w][lane * 2 + 1] = s1;
    __syncthreads();
    if (t < 128) atomicAdd(&sums[t], sh[0][t] + sh[1][t] + sh[2][t] + sh[3][t]);
    __syncthreads();
    sh[w][lane * 2] = q0; sh[w][lane * 2 + 1] = q1;
    __syncthreads();
    if (t < 128) atomicAdd(&sums[128 + t], sh[0][t] + sh[1][t] + sh[2][t] + sh[3][t]);
}

__global__ void k_bn_finalize(const float* __restrict__ sums,
                              const float* __restrict__ gamma,
                              const float* __restrict__ beta,
                              float* __restrict__ scale,
                              float* __restrict__ shift) {
    int t = threadIdx.x;  // 128 threads
    float mean = sums[t] * (1.0f / N_NODES);
    float var  = sums[128 + t] * (1.0f / N_NODES) - mean * mean;
    float sc = gamma[t] * rsqrtf(var + 1e-5f);
    scale[t] = sc;
    shift[t] = beta[t] - mean * sc;
}

// Fold BN affine into weights
__global__ __launch_bounds__(256) void k_prep_w(const float* __restrict__ w_l,
                                                const float* __restrict__ b_l,
                                                const float* __restrict__ w_r,
                                                const float* __restrict__ b_r,
                                                const float* __restrict__ scale,
                                                const float* __restrict__ shift,
                                                float* __restrict__ Wp,
                                                float* __restrict__ bp) {
    const int t = threadIdx.x;
    const int lane = t & 63;
    const int o = blockIdx.x * 4 + (t >> 6);       // 0..511
    const float* wrow = (o < NHID) ? (w_l + (size_t)o * F_IN)
                                   : (w_r + (size_t)(o - NHID) * F_IN);
    float bo = (o < NHID) ? b_l[o] : b_r[o - NHID];
    float2 wv = *(const float2*)(wrow + lane * 2);
    float sc0 = scale[lane * 2], sc1 = scale[lane * 2 + 1];
    Wp[(size_t)o * F_IN + lane * 2]     = wv.x * sc0;
    Wp[(size_t)o * F_IN + lane * 2 + 1] = wv.y * sc1;
    float part = shift[lane * 2] * wv.x + shift[lane * 2 + 1] * wv.y;
    #pragma unroll
    for (int m = 1; m < 64; m <<= 1) part += __shfl_xor(part, m, 64);
    if (lane == 0) bp[o] = bo + part;
}

// ---------------------------------------------------------------- GEMM (fp32)
// cols [0,256) -> xs (bf16 output), cols [256,512) -> xd (fp32 output)
__global__ __launch_bounds__(256) void k_gemm(const float* __restrict__ x,
                                              const float* __restrict__ Wp,
                                              const float* __restrict__ bp,
                                              unsigned short* __restrict__ xs_bf,
                                              float* __restrict__ xd_f) {
    __shared__ __align__(16) float As[32][68];
    __shared__ __align__(16) float Bs[32][68];
    const int t = threadIdx.x;
    const int m0 = blockIdx.y * 64;
    const int n0 = blockIdx.x * 64;
    const int tx = t & 15, ty = t >> 4;
    float acc[4][4] = {};
    for (int kt = 0; kt < 4; ++kt) {
        const int k0 = kt * 32;
        #pragma unroll
        for (int q = 0; q < 2; ++q) {
            int f = t + q * 256;
            int row = f >> 3;
            int kq = (f & 7) << 2;
            float4 av = *(const float4*)(x  + (size_t)(m0 + row) * F_IN + k0 + kq);
            float4 bv = *(const float4*)(Wp + (size_t)(n0 + row) * F_IN + k0 + kq);
            As[kq + 0][row] = av.x; As[kq + 1][row] = av.y;
            As[kq + 2][row] = av.z; As[kq + 3][row] = av.w;
            Bs[kq + 0][row] = bv.x; Bs[kq + 1][row] = bv.y;
            Bs[kq + 2][row] = bv.z; Bs[kq + 3][row] = bv.w;
        }
        __syncthreads();
        #pragma unroll
        for (int kk = 0; kk < 32; ++kk) {
            float4 a4 = *(const float4*)&As[kk][ty * 4];
            float4 b4 = *(const float4*)&Bs[kk][tx * 4];
            float a[4] = {a4.x, a4.y, a4.z, a4.w};
            float b[4] = {b4.x, b4.y, b4.z, b4.w};
            #pragma unroll
            for (int i = 0; i < 4; ++i)
                #pragma unroll
                for (int j = 0; j < 4; ++j)
                    acc[i][j] = fmaf(a[i], b[j], acc[i][j]);
        }
        __syncthreads();
    }
    float4 bb = *(const float4*)(bp + n0 + tx * 4);
    float bcol[4] = {bb.x, bb.y, bb.z, bb.w};
    #pragma unroll
    for (int i = 0; i < 4; ++i) {
        float o0 = acc[i][0] + bcol[0], o1 = acc[i][1] + bcol[1];
        float o2 = acc[i][2] + bcol[2], o3 = acc[i][3] + bcol[3];
        int row = m0 + ty * 4 + i;
        if (n0 < NHID) {
            unsigned lo = (unsigned)f2bf(o0) | ((unsigned)f2bf(o1) << 16);
            unsigned hi = (unsigned)f2bf(o2) | ((unsigned)f2bf(o3) << 16);
            uint2 pk; pk.x = lo; pk.y = hi;
            *(uint2*)(xs_bf + (size_t)row * NHID + n0 + tx * 4) = pk;
        } else {
            float4 o = {o0, o1, o2, o3};
            *(float4*)(xd_f + (size_t)row * NHID + (n0 - NHID) + tx * 4) = o;
        }
    }
}

// ---------------------------------------------------------------- CSR build
__global__ __launch_bounds__(256) void k_hist(const int* __restrict__ ei,
                                              int* __restrict__ counts) {
    int e = blockIdx.x * 256 + threadIdx.x;
    atomicAdd(&counts[ei[N_EDGES + e]], 1);
}

__global__ __launch_bounds__(256) void k_scan1(const int* __restrict__ counts,
                                               int* __restrict__ row_start,
                                               int* __restrict__ blocksums) {
    __shared__ int sh[256];
    int t = threadIdx.x;
    int i = blockIdx.x * 256 + t;
    int v = counts[i];
    sh[t] = v;
    __syncthreads();
    for (int off = 1; off < 256; off <<= 1) {
        int add = (t >= off) ? sh[t - off] : 0;
        __syncthreads();
        sh[t] += add;
        __syncthreads();
    }
    row_start[i] = sh[t] - v;
    if (t == 255) blocksums[blockIdx.x] = sh[255];
}

__global__ void k_scan2(int* __restrict__ blocksums) {
    __shared__ int sh[256];
    int t = threadIdx.x;
    int v = blocksums[t];
    sh[t] = v;
    __syncthreads();
    for (int off = 1; off < 256; off <<= 1) {
        int add = (t >= off) ? sh[t - off] : 0;
        __syncthreads();
        sh[t] += add;
        __syncthreads();
    }
    blocksums[t] = sh[t] - v;
}

__global__ __launch_bounds__(256) void k_scan3(int* __restrict__ row_start,
                                               const int* __restrict__ blocksums,
                                               int* __restrict__ cursor) {
    int i = blockIdx.x * 256 + threadIdx.x;
    int v = row_start[i] + blocksums[blockIdx.x];
    row_start[i] = v;
    cursor[i] = v;
}

__global__ __launch_bounds__(256) void k_scatter(const int* __restrict__ ei,
                                                 int* __restrict__ cursor,
                                                 int* __restrict__ csr) {
    int e = blockIdx.x * 256 + threadIdx.x;
    int s = ei[e];
    int d = ei[N_EDGES + e];
    int pos = atomicAdd(&cursor[d], 1);
    csr[pos] = s;
}

// ---------------------------------------------------------------- aggregation
struct OS { float m, s, ax, ay, az, aw; };

__device__ inline void os_upd(OS& o, uint2 v, const float4& xd4, const float4& att4) {
    float c0 = __uint_as_float(v.x << 16);
    float c1 = __uint_as_float(v.x & 0xffff0000u);
    float c2 = __uint_as_float(v.y << 16);
    float c3 = __uint_as_float(v.y & 0xffff0000u);
    float e0 = c0 + xd4.x; e0 = (e0 > 0.f) ? e0 : NEG * e0;
    float e1 = c1 + xd4.y; e1 = (e1 > 0.f) ? e1 : NEG * e1;
    float e2 = c2 + xd4.z; e2 = (e2 > 0.f) ? e2 : NEG * e2;
    float e3 = c3 + xd4.w; e3 = (e3 > 0.f) ? e3 : NEG * e3;
    float d = e0 * att4.x + e1 * att4.y + e2 * att4.z + e3 * att4.w;
    d += __shfl_xor(d, 1, 64);
    d += __shfl_xor(d, 2, 64);
    d += __shfl_xor(d, 4, 64);
    d += __shfl_xor(d, 8, 64);               // 16-lane head-group logit
    if (d > o.m + 8.0f) {                    // defer-max: rescale only on big growth
        float f = __expf(o.m - d);           // first item: exp(-inf)=0 zeroes state
        o.s *= f; o.ax *= f; o.ay *= f; o.az *= f; o.aw *= f;
        o.m = d;
    }
    float p = __expf(d - o.m);               // bounded by e^8
    o.s += p;
    o.ax = fmaf(p, c0, o.ax);
    o.ay = fmaf(p, c1, o.ay);
    o.az = fmaf(p, c2, o.az);
    o.aw = fmaf(p, c3, o.aw);
}

// one wave per dst node; lane l owns cols [4l,4l+4) of the 256-wide row (head = l>>4)
__global__ __launch_bounds__(256) void k_aggregate(const unsigned short* __restrict__ xs_bf,
                                                   const float* __restrict__ xd_f,
                                                   const int* __restrict__ row_start,
                                                   const int* __restrict__ counts,
                                                   const int* __restrict__ csr,
                                                   const float* __restrict__ att,
                                                   const float* __restrict__ bias,
                                                   float* __restrict__ out) {
    const int t = threadIdx.x;
    const int lane = t & 63;
    const int node = blockIdx.x * 4 + (t >> 6);
    const float4 att4 = *(const float4*)(att + lane * 4);
    fx4 xdv = __builtin_nontemporal_load((const fx4*)(xd_f + (size_t)node * NHID + lane * 4));
    const float4 xd4 = {xdv.x, xdv.y, xdv.z, xdv.w};
    const int start = row_start[node];
    const int deg = counts[node];
    const int total = deg + 1;               // + self loop (last item)
    OS A = {-INFINITY, 0.f, 0.f, 0.f, 0.f, 0.f};
    OS B = {-INFINITY, 0.f, 0.f, 0.f, 0.f, 0.f};
    for (int base = 0; base < total; base += 64) {
        const int cnt = min(64, total - base);
        int idx = node;                       // items >= deg are the self loop
        const int item = base + lane;
        if (lane < cnt && item < deg)
            idx = __builtin_nontemporal_load(csr + start + item);
        // dual-state pipeline, prefetch depth 2
        int s0 = __shfl(idx, 0, 64);
        uint2 q0 = *(const uint2*)(xs_bf + (size_t)s0 * NHID + lane * 4);
        uint2 q1 = q0;
        if (cnt > 1) {
            int s1 = __shfl(idx, 1, 64);
            q1 = *(const uint2*)(xs_bf + (size_t)s1 * NHID + lane * 4);
        }
        for (int j = 0; j < cnt; j += 2) {
            uint2 c0 = q0, c1 = q1;
            if (j + 2 < cnt) {
                int sn = __shfl(idx, j + 2, 64);
                q0 = *(const uint2*)(xs_bf + (size_t)sn * NHID + lane * 4);
            }
            if (j + 3 < cnt) {
                int sn = __shfl(idx, j + 3, 64);
                q1 = *(const uint2*)(xs_bf + (size_t)sn * NHID + lane * 4);
            }
            os_upd(A, c0, xd4, att4);
            if (j + 1 < cnt) os_upd(B, c1, xd4, att4);
        }
    }
    // exact merge of the two online-softmax states (B may be empty: m=-inf -> fB=0)
    float mn = fmaxf(A.m, B.m);
    float fA = __expf(A.m - mn), fB = __expf(B.m - mn);
    float s  = A.s  * fA + B.s  * fB;
    float ax = A.ax * fA + B.ax * fB;
    float ay = A.ay * fA + B.ay * fB;
    float az = A.az * fA + B.az * fB;
    float aw = A.aw * fA + B.aw * fB;
    float inv = 1.0f / s;
    float ox = ax * inv, oy = ay * inv, oz = az * inv, ow = aw * inv;
    ox += __shfl_xor(ox, 16, 64); ox += __shfl_xor(ox, 32, 64);  // head mean
    oy += __shfl_xor(oy, 16, 64); oy += __shfl_xor(oy, 32, 64);
    oz += __shfl_xor(oz, 16, 64); oz += __shfl_xor(oz, 32, 64);
    ow += __shfl_xor(ow, 16, 64); ow += __shfl_xor(ow, 32, 64);
    const float4 b4 = *(const float4*)(bias + (lane & 15) * 4);
    ox = ox * 0.25f + b4.x; oy = oy * 0.25f + b4.y;
    oz = oz * 0.25f + b4.z; ow = ow * 0.25f + b4.w;
    ox = (ox > 0.f) ? ox : expm1f(ox);
    oy = (oy > 0.f) ? oy : expm1f(oy);
    oz = (oz > 0.f) ? oz : expm1f(oz);
    ow = (ow > 0.f) ? ow : expm1f(ow);
    if (lane < 16) {
        fx4 o = {ox, oy, oz, ow};
        __builtin_nontemporal_store(o, (fx4*)(out + (size_t)node * HID + lane * 4));
    }
}

// ---------------------------------------------------------------- launch
extern "C" void kernel_launch(void* const* d_in, const int* in_sizes, int n_in,
                              void* d_out, int out_size, void* d_ws, size_t ws_size,
                              hipStream_t stream) {
    const float* x     = (const float*)d_in[0];
    const int*   ei    = (const int*)d_in[1];
    const float* gamma = (const float*)d_in[4];
    const float* beta  = (const float*)d_in[5];
    const float* w_l   = (const float*)d_in[6];
    const float* b_l   = (const float*)d_in[7];
    const float* w_r   = (const float*)d_in[8];
    const float* b_r   = (const float*)d_in[9];
    const float* att   = (const float*)d_in[10];
    const float* bias  = (const float*)d_in[11];
    float* out = (float*)d_out;

    char* ws = (char*)d_ws;
    unsigned short* xs_bf = (unsigned short*)ws;                  // 32 MB
    float* xd_f  = (float*)(ws + (size_t)N_NODES * NHID * 2);     // 64 MB
    float* Wp    = xd_f + (size_t)N_NODES * NHID;                 // 512*128
    float* bp    = Wp + 512 * 128;                                // 512
    float* scale = bp + 512;                                      // 128
    float* shift = scale + 128;                                   // 128
    float* sums  = shift + 128;                                   // 256
    int* counts    = (int*)(sums + 256);                          // 65536
    int* row_start = counts + N_NODES;                            // 65536
    int* cursor    = row_start + N_NODES;                         // 65536
    int* blocksums = cursor + N_NODES;                            // 256
    int* csr       = blocksums + 256;                             // 1048576

    hipMemsetAsync(sums, 0, (256 + N_NODES) * sizeof(float), stream);

    k_bn_stats<<<256, 256, 0, stream>>>(x, sums);
    k_bn_finalize<<<1, 128, 0, stream>>>(sums, gamma, beta, scale, shift);
    k_prep_w<<<128, 256, 0, stream>>>(w_l, b_l, w_r, b_r, scale, shift, Wp, bp);
    k_gemm<<<dim3(8, 1024), 256, 0, stream>>>(x, Wp, bp, xs_bf, xd_f);

    k_hist<<<N_EDGES / 256, 256, 0, stream>>>(ei, counts);
    k_scan1<<<256, 256, 0, stream>>>(counts, row_start, blocksums);
    k_scan2<<<1, 256, 0, stream>>>(blocksums);
    k_scan3<<<256, 256, 0, stream>>>(row_start, blocksums, cursor);
    k_scatter<<<N_EDGES / 256, 256, 0, stream>>>(ei, cursor, csr);

    k_aggregate<<<N_NODES / 4, 256, 0, stream>>>(xs_bf, xd_f, row_start, counts, csr,
                                                 att, bias, out);
}

// Round 3
// 238.782 us; speedup vs baseline: 1.8556x; 1.6669x over previous
//
#include <hip/hip_runtime.h>
#include <hip/hip_bf16.h>

#define N_NODES 65536
#define N_EDGES 1048576
#define F_IN    128
#define HEADS   4
#define HID     64
#define NHID    256   // HEADS*HID
#define NEG     0.2f
#define NBUCK   1024  // coarse buckets = dst>>6
#define BCAP    2048  // slots per bucket (expected 1024, overflow impossible in practice)

typedef float fx4 __attribute__((ext_vector_type(4)));
typedef short bf16x8 __attribute__((ext_vector_type(8)));
typedef float f32x4 __attribute__((ext_vector_type(4)));

__device__ inline unsigned short f2bf(float f) {
    unsigned u = __float_as_uint(f);
    u += 0x7fff + ((u >> 16) & 1);          // round-to-nearest-even
    return (unsigned short)(u >> 16);
}
__device__ inline float bf2f(unsigned short h) {
    return __uint_as_float((unsigned)h << 16);
}

// ---------------------------------------------------------------- BN stats + x -> bf16 hi/lo (pre-swizzled)
// swizzle: within each 256B row, 16B slot s stored at slot s ^ (row&7)
__global__ __launch_bounds__(256) void k_bn_stats(const float* __restrict__ x,
                                                  float* __restrict__ sums,
                                                  unsigned short* __restrict__ xhi,
                                                  unsigned short* __restrict__ xlo) {
    const int t = threadIdx.x;
    const int lane = t & 63;
    const int w = t >> 6;
    const int wid = blockIdx.x * 4 + w;            // 0..1023 global wave id
    float s0 = 0.f, s1 = 0.f, q0 = 0.f, q1 = 0.f;
    for (int i = 0; i < 64; ++i) {
        int r = wid + i * 1024;
        float2 v = *(const float2*)(x + (size_t)r * F_IN + lane * 2);
        s0 += v.x; q0 += v.x * v.x;
        s1 += v.y; q1 += v.y * v.y;
        unsigned short h0 = f2bf(v.x), h1 = f2bf(v.y);
        unsigned short l0 = f2bf(v.x - bf2f(h0)), l1 = f2bf(v.y - bf2f(h1));
        int slot = (lane >> 2) ^ (r & 7);
        int idx = r * 64 + slot * 4 + (lane & 3);  // uint units
        ((unsigned*)xhi)[idx] = (unsigned)h0 | ((unsigned)h1 << 16);
        ((unsigned*)xlo)[idx] = (unsigned)l0 | ((unsigned)l1 << 16);
    }
    __shared__ float sh[4][128];
    sh[w][lane * 2] = s0; sh[w][lane * 2 + 1] = s1;
    __syncthreads();
    if (t < 128) atomicAdd(&sums[t], sh[0][t] + sh[1][t] + sh[2][t] + sh[3][t]);
    __syncthreads();
    sh[w][lane * 2] = q0; sh[w][lane * 2 + 1] = q1;
    __syncthreads();
    if (t < 128) atomicAdd(&sums[128 + t], sh[0][t] + sh[1][t] + sh[2][t] + sh[3][t]);
}

__global__ void k_bn_finalize(const float* __restrict__ sums,
                              const float* __restrict__ gamma,
                              const float* __restrict__ beta,
                              float* __restrict__ scale,
                              float* __restrict__ shift) {
    int t = threadIdx.x;  // 128 threads
    float mean = sums[t] * (1.0f / N_NODES);
    float var  = sums[128 + t] * (1.0f / N_NODES) - mean * mean;
    float sc = gamma[t] * rsqrtf(var + 1e-5f);
    scale[t] = sc;
    shift[t] = beta[t] - mean * sc;
}

// Fold BN affine into weights; split to bf16 hi/lo, pre-swizzled like x
__global__ __launch_bounds__(256) void k_prep_w(const float* __restrict__ w_l,
                                                const float* __restrict__ b_l,
                                                const float* __restrict__ w_r,
                                                const float* __restrict__ b_r,
                                                const float* __restrict__ scale,
                                                const float* __restrict__ shift,
                                                unsigned short* __restrict__ Whi,
                                                unsigned short* __restrict__ Wlo,
                                                float* __restrict__ bp) {
    const int t = threadIdx.x;
    const int lane = t & 63;
    const int o = blockIdx.x * 4 + (t >> 6);       // 0..511
    const float* wrow = (o < NHID) ? (w_l + (size_t)o * F_IN)
                                   : (w_r + (size_t)(o - NHID) * F_IN);
    float bo = (o < NHID) ? b_l[o] : b_r[o - NHID];
    float2 wv = *(const float2*)(wrow + lane * 2);
    float w0 = wv.x * scale[lane * 2], w1 = wv.y * scale[lane * 2 + 1];
    unsigned short h0 = f2bf(w0), h1 = f2bf(w1);
    unsigned short l0 = f2bf(w0 - bf2f(h0)), l1 = f2bf(w1 - bf2f(h1));
    int slot = (lane >> 2) ^ (o & 7);
    int idx = o * 64 + slot * 4 + (lane & 3);
    ((unsigned*)Whi)[idx] = (unsigned)h0 | ((unsigned)h1 << 16);
    ((unsigned*)Wlo)[idx] = (unsigned)l0 | ((unsigned)l1 << 16);
    float part = shift[lane * 2] * wv.x + shift[lane * 2 + 1] * wv.y;  // raw W for bias fold
    #pragma unroll
    for (int m = 1; m < 64; m <<= 1) part += __shfl_xor(part, m, 64);
    if (lane == 0) bp[o] = bo + part;
}

// ---------------------------------------------------------------- MFMA GEMM
// D = (Ahi+Alo)(Bhi+Blo) ~= Ahi*Bhi + Ahi*Blo + Alo*Bhi  (fp32 accumulate)
// BM=BN=128, K=128 single-shot. 512 threads = 8 waves (2M x 4N), wave tile 64x32.
__global__ __launch_bounds__(512) void k_gemm_mfma(const unsigned short* __restrict__ xhi,
                                                   const unsigned short* __restrict__ xlo,
                                                   const unsigned short* __restrict__ Whi,
                                                   const unsigned short* __restrict__ Wlo,
                                                   const float* __restrict__ bp,
                                                   unsigned short* __restrict__ xs_bf,
                                                   unsigned short* __restrict__ xd_bf) {
    __shared__ __align__(16) char lds[131072];     // Ahi|Alo|Bhi|Blo, 32KB each
    const int t = threadIdx.x;
    const int bid = blockIdx.x;                    // 2048
    // XCD-partition: xcd = bid&7 owns M-chunk [xcd*64*128, ...): A stays in its L2
    const int mb = (bid & 7) * 64 + ((bid >> 3) >> 2);   // 0..511
    const int nb = (bid >> 3) & 3;                 // 0..3
    const int m0 = mb * 128, n0 = nb * 128;
    {
        const uint4* srcs[4] = {
            (const uint4*)(xhi + (size_t)m0 * 128),
            (const uint4*)(xlo + (size_t)m0 * 128),
            (const uint4*)(Whi + (size_t)n0 * 128),
            (const uint4*)(Wlo + (size_t)n0 * 128)};
        #pragma unroll
        for (int c = 0; c < 4; ++c) {
            uint4* dst = (uint4*)(lds + c * 32768);
            #pragma unroll
            for (int q = 0; q < 4; ++q) {
                int i = q * 512 + t;               // 16B units, 2048 per 32KB chunk
                dst[i] = srcs[c][i];
            }
        }
    }
    __syncthreads();
    const int wvi = t >> 6, lane = t & 63;
    const int wm = wvi >> 2, wn = wvi & 3;         // 2 x 4 wave grid
    const int lg = lane >> 4, lr = lane & 15;
    f32x4 acc[4][2] = {};                          // mi(4 x 16 rows), nj(2 x 16 cols)
    #pragma unroll
    for (int ks = 0; ks < 4; ++ks) {
        bf16x8 ah[4], al[4], bh[2], bl[2];
        #pragma unroll
        for (int mi = 0; mi < 4; ++mi) {
            int r = wm * 64 + mi * 16 + lr;
            int off = r * 256 + ((((ks << 2) + lg) ^ (r & 7)) << 4);
            ah[mi] = *(const bf16x8*)(lds + off);
            al[mi] = *(const bf16x8*)(lds + 32768 + off);
        }
        #pragma unroll
        for (int nj = 0; nj < 2; ++nj) {
            int r = wn * 32 + nj * 16 + lr;
            int off = r * 256 + ((((ks << 2) + lg) ^ (r & 7)) << 4);
            bh[nj] = *(const bf16x8*)(lds + 65536 + off);
            bl[nj] = *(const bf16x8*)(lds + 98304 + off);
        }
        #pragma unroll
        for (int mi = 0; mi < 4; ++mi)
            #pragma unroll
            for (int nj = 0; nj < 2; ++nj) {
                acc[mi][nj] = __builtin_amdgcn_mfma_f32_16x16x32_bf16(ah[mi], bh[nj], acc[mi][nj], 0, 0, 0);
                acc[mi][nj] = __builtin_amdgcn_mfma_f32_16x16x32_bf16(ah[mi], bl[nj], acc[mi][nj], 0, 0, 0);
                acc[mi][nj] = __builtin_amdgcn_mfma_f32_16x16x32_bf16(al[mi], bh[nj], acc[mi][nj], 0, 0, 0);
            }
    }
    // epilogue: +bias, bf16, store. n0<256 -> xs half, else xd half (block-uniform)
    unsigned short* outp = (n0 < NHID) ? xs_bf : xd_bf;
    const int ncol0 = n0 & 255;
    #pragma unroll
    for (int nj = 0; nj < 2; ++nj) {
        int nc = wn * 32 + nj * 16 + lr;           // 0..127 within block
        float bcol = bp[n0 + nc];
        #pragma unroll
        for (int mi = 0; mi < 4; ++mi) {
            #pragma unroll
            for (int r = 0; r < 4; ++r) {
                int m = m0 + wm * 64 + mi * 16 + lg * 4 + r;   // C/D: col=lane&15, row=4*(lane>>4)+reg
                outp[(size_t)m * NHID + ncol0 + nc] = f2bf(acc[mi][nj][r] + bcol);
            }
        }
    }
}

// ---------------------------------------------------------------- CSR build (hierarchical, few atomics)
// coarse: partition edges into 1024 buckets by dst>>6; LDS hist + 1024 global atomics per block
__global__ __launch_bounds__(256) void k_coarse(const int* __restrict__ ei,
                                                int* __restrict__ ccnt,
                                                unsigned* __restrict__ cbuf) {
    __shared__ int cnt[NBUCK];
    __shared__ int base[NBUCK];
    const int t = threadIdx.x;
    for (int i = t; i < NBUCK; i += 256) cnt[i] = 0;
    __syncthreads();
    const int e0 = blockIdx.x * 8192;
    int myrank[32];
    #pragma unroll
    for (int k = 0; k < 32; ++k) {
        int d = ei[N_EDGES + e0 + k * 256 + t];
        myrank[k] = atomicAdd(&cnt[d >> 6], 1);
    }
    __syncthreads();
    for (int i = t; i < NBUCK; i += 256)
        base[i] = (i << 11) + atomicAdd(&ccnt[i], cnt[i]);
    __syncthreads();
    #pragma unroll
    for (int k = 0; k < 32; ++k) {
        int e = e0 + k * 256 + t;
        int s = ei[e];
        int d = ei[N_EDGES + e];
        unsigned pos = (unsigned)(base[d >> 6] + myrank[k]);
        if ((pos >> 11) == (unsigned)(d >> 6))         // overflow guard (stat. impossible)
            cbuf[pos] = (unsigned)s | ((unsigned)(d & 63) << 16);
    }
}

// per-bucket exact per-node counts (LDS atomics only)
__global__ __launch_bounds__(256) void k_fineA(const unsigned* __restrict__ cbuf,
                                               const int* __restrict__ ccnt,
                                               int* __restrict__ counts) {
    __shared__ int nc[64];
    const int t = threadIdx.x;
    const int b = blockIdx.x;
    if (t < 64) nc[t] = 0;
    __syncthreads();
    const int cnt = min(ccnt[b], BCAP);
    const unsigned* p = cbuf + (size_t)b * BCAP;
    for (int e = t; e < cnt; e += 256)
        atomicAdd(&nc[(p[e] >> 16) & 63], 1);
    __syncthreads();
    if (t < 64) counts[b * 64 + t] = nc[t];
}

__global__ __launch_bounds__(256) void k_scan1(const int* __restrict__ counts,
                                               int* __restrict__ row_start,
                                               int* __restrict__ blocksums) {
    __shared__ int sh[256];
    int t = threadIdx.x;
    int i = blockIdx.x * 256 + t;
    int v = counts[i];
    sh[t] = v;
    __syncthreads();
    for (int off = 1; off < 256; off <<= 1) {
        int add = (t >= off) ? sh[t - off] : 0;
        __syncthreads();
        sh[t] += add;
        __syncthreads();
    }
    row_start[i] = sh[t] - v;
    if (t == 255) blocksums[blockIdx.x] = sh[255];
}

__global__ void k_scan2(int* __restrict__ blocksums) {
    __shared__ int sh[256];
    int t = threadIdx.x;
    int v = blocksums[t];
    sh[t] = v;
    __syncthreads();
    for (int off = 1; off < 256; off <<= 1) {
        int add = (t >= off) ? sh[t - off] : 0;
        __syncthreads();
        sh[t] += add;
        __syncthreads();
    }
    blocksums[t] = sh[t] - v;
}

__global__ __launch_bounds__(256) void k_scan3(int* __restrict__ row_start,
                                               const int* __restrict__ blocksums) {
    int i = blockIdx.x * 256 + threadIdx.x;
    row_start[i] += blocksums[blockIdx.x];
}

// per-bucket scatter with LDS cursors (csr order within a node is arbitrary; softmax invariant)
__global__ __launch_bounds__(256) void k_fineB(const unsigned* __restrict__ cbuf,
                                               const int* __restrict__ ccnt,
                                               const int* __restrict__ row_start,
                                               int* __restrict__ csr) {
    __shared__ int rs[64];
    __shared__ int cur[64];
    const int t = threadIdx.x;
    const int b = blockIdx.x;
    if (t < 64) { rs[t] = row_start[b * 64 + t]; cur[t] = 0; }
    __syncthreads();
    const int cnt = min(ccnt[b], BCAP);
    const unsigned* p = cbuf + (size_t)b * BCAP;
    for (int e = t; e < cnt; e += 256) {
        unsigned w2 = p[e];
        int d = (w2 >> 16) & 63;
        int r = atomicAdd(&cur[d], 1);
        csr[rs[d] + r] = (int)(w2 & 0xffffu);
    }
}

// ---------------------------------------------------------------- aggregation
struct OS { float m, s, ax, ay, az, aw; };

__device__ inline void os_upd(OS& o, uint2 v, const float4& xd4, const float4& att4) {
    float c0 = __uint_as_float(v.x << 16);
    float c1 = __uint_as_float(v.x & 0xffff0000u);
    float c2 = __uint_as_float(v.y << 16);
    float c3 = __uint_as_float(v.y & 0xffff0000u);
    float e0 = c0 + xd4.x; e0 = (e0 > 0.f) ? e0 : NEG * e0;
    float e1 = c1 + xd4.y; e1 = (e1 > 0.f) ? e1 : NEG * e1;
    float e2 = c2 + xd4.z; e2 = (e2 > 0.f) ? e2 : NEG * e2;
    float e3 = c3 + xd4.w; e3 = (e3 > 0.f) ? e3 : NEG * e3;
    float d = e0 * att4.x + e1 * att4.y + e2 * att4.z + e3 * att4.w;
    d += __shfl_xor(d, 1, 64);
    d += __shfl_xor(d, 2, 64);
    d += __shfl_xor(d, 4, 64);
    d += __shfl_xor(d, 8, 64);               // 16-lane head-group logit
    if (d > o.m + 8.0f) {                    // defer-max
        float f = __expf(o.m - d);
        o.s *= f; o.ax *= f; o.ay *= f; o.az *= f; o.aw *= f;
        o.m = d;
    }
    float p = __expf(d - o.m);
    o.s += p;
    o.ax = fmaf(p, c0, o.ax);
    o.ay = fmaf(p, c1, o.ay);
    o.az = fmaf(p, c2, o.az);
    o.aw = fmaf(p, c3, o.aw);
}

__global__ __launch_bounds__(256) void k_aggregate(const unsigned short* __restrict__ xs_bf,
                                                   const unsigned short* __restrict__ xd_bf,
                                                   const int* __restrict__ row_start,
                                                   const int* __restrict__ counts,
                                                   const int* __restrict__ csr,
                                                   const float* __restrict__ att,
                                                   const float* __restrict__ bias,
                                                   float* __restrict__ out) {
    const int t = threadIdx.x;
    const int lane = t & 63;
    const int node = blockIdx.x * 4 + (t >> 6);
    const float4 att4 = *(const float4*)(att + lane * 4);
    uint2 xdw = *(const uint2*)(xd_bf + (size_t)node * NHID + lane * 4);
    const float4 xd4 = {__uint_as_float(xdw.x << 16), __uint_as_float(xdw.x & 0xffff0000u),
                        __uint_as_float(xdw.y << 16), __uint_as_float(xdw.y & 0xffff0000u)};
    const int start = row_start[node];
    const int deg = counts[node];
    const int total = deg + 1;               // + self loop (last item)
    OS A = {-INFINITY, 0.f, 0.f, 0.f, 0.f, 0.f};
    OS B = {-INFINITY, 0.f, 0.f, 0.f, 0.f, 0.f};
    for (int base = 0; base < total; base += 64) {
        const int cnt = min(64, total - base);
        int idx = node;
        const int item = base + lane;
        if (lane < cnt && item < deg)
            idx = __builtin_nontemporal_load(csr + start + item);
        int s0 = __shfl(idx, 0, 64);
        uint2 q0 = *(const uint2*)(xs_bf + (size_t)s0 * NHID + lane * 4);
        uint2 q1 = q0;
        if (cnt > 1) {
            int s1 = __shfl(idx, 1, 64);
            q1 = *(const uint2*)(xs_bf + (size_t)s1 * NHID + lane * 4);
        }
        for (int j = 0; j < cnt; j += 2) {
            uint2 c0 = q0, c1 = q1;
            if (j + 2 < cnt) {
                int sn = __shfl(idx, j + 2, 64);
                q0 = *(const uint2*)(xs_bf + (size_t)sn * NHID + lane * 4);
            }
            if (j + 3 < cnt) {
                int sn = __shfl(idx, j + 3, 64);
                q1 = *(const uint2*)(xs_bf + (size_t)sn * NHID + lane * 4);
            }
            os_upd(A, c0, xd4, att4);
            if (j + 1 < cnt) os_upd(B, c1, xd4, att4);
        }
    }
    float mn = fmaxf(A.m, B.m);
    float fA = __expf(A.m - mn), fB = __expf(B.m - mn);
    float s  = A.s  * fA + B.s  * fB;
    float ax = A.ax * fA + B.ax * fB;
    float ay = A.ay * fA + B.ay * fB;
    float az = A.az * fA + B.az * fB;
    float aw = A.aw * fA + B.aw * fB;
    float inv = 1.0f / s;
    float ox = ax * inv, oy = ay * inv, oz = az * inv, ow = aw * inv;
    ox += __shfl_xor(ox, 16, 64); ox += __shfl_xor(ox, 32, 64);  // head mean
    oy += __shfl_xor(oy, 16, 64); oy += __shfl_xor(oy, 32, 64);
    oz += __shfl_xor(oz, 16, 64); oz += __shfl_xor(oz, 32, 64);
    ow += __shfl_xor(ow, 16, 64); ow += __shfl_xor(ow, 32, 64);
    const float4 b4 = *(const float4*)(bias + (lane & 15) * 4);
    ox = ox * 0.25f + b4.x; oy = oy * 0.25f + b4.y;
    oz = oz * 0.25f + b4.z; ow = ow * 0.25f + b4.w;
    ox = (ox > 0.f) ? ox : expm1f(ox);
    oy = (oy > 0.f) ? oy : expm1f(oy);
    oz = (oz > 0.f) ? oz : expm1f(oz);
    ow = (ow > 0.f) ? ow : expm1f(ow);
    if (lane < 16) {
        fx4 o = {ox, oy, oz, ow};
        __builtin_nontemporal_store(o, (fx4*)(out + (size_t)node * HID + lane * 4));
    }
}

// ---------------------------------------------------------------- launch
extern "C" void kernel_launch(void* const* d_in, const int* in_sizes, int n_in,
                              void* d_out, int out_size, void* d_ws, size_t ws_size,
                              hipStream_t stream) {
    const float* x     = (const float*)d_in[0];
    const int*   ei    = (const int*)d_in[1];
    const float* gamma = (const float*)d_in[4];
    const float* beta  = (const float*)d_in[5];
    const float* w_l   = (const float*)d_in[6];
    const float* b_l   = (const float*)d_in[7];
    const float* w_r   = (const float*)d_in[8];
    const float* b_r   = (const float*)d_in[9];
    const float* att   = (const float*)d_in[10];
    const float* bias  = (const float*)d_in[11];
    float* out = (float*)d_out;

    char* ws = (char*)d_ws;
    unsigned short* xs_bf = (unsigned short*)ws;                        // 32 MB
    unsigned short* xd_bf = xs_bf + (size_t)N_NODES * NHID;             // 32 MB
    unsigned short* xhi   = xd_bf + (size_t)N_NODES * NHID;             // 16 MB
    unsigned short* xlo   = xhi + (size_t)N_NODES * F_IN;               // 16 MB
    unsigned short* Whi   = xlo + (size_t)N_NODES * F_IN;               // 128 KB
    unsigned short* Wlo   = Whi + 512 * F_IN;                           // 128 KB
    float* bp    = (float*)(Wlo + 512 * F_IN);                          // 512
    float* scale = bp + 512;                                            // 128
    float* shift = scale + 128;                                         // 128
    float* sums  = shift + 128;                                         // 256  (memset from here)
    int* counts    = (int*)(sums + 256);                                // 65536
    int* ccnt      = counts + N_NODES;                                  // 1024 (memset to here)
    int* row_start = ccnt + NBUCK;                                      // 65536
    int* blocksums = row_start + N_NODES;                               // 256
    int* csr       = blocksums + 256;                                   // 1048576
    unsigned* cbuf = (unsigned*)(csr + N_EDGES);                        // 1024*2048 = 8 MB

    // zero BN sums + per-node counts + bucket counts (contiguous)
    hipMemsetAsync(sums, 0, (256 + N_NODES + NBUCK) * sizeof(float), stream);

    k_bn_stats<<<256, 256, 0, stream>>>(x, sums, xhi, xlo);
    k_bn_finalize<<<1, 128, 0, stream>>>(sums, gamma, beta, scale, shift);
    k_prep_w<<<128, 256, 0, stream>>>(w_l, b_l, w_r, b_r, scale, shift, Whi, Wlo, bp);
    k_gemm_mfma<<<2048, 512, 0, stream>>>(xhi, xlo, Whi, Wlo, bp, xs_bf, xd_bf);

    k_coarse<<<N_EDGES / 8192, 256, 0, stream>>>(ei, ccnt, cbuf);
    k_fineA<<<NBUCK, 256, 0, stream>>>(cbuf, ccnt, counts);
    k_scan1<<<256, 256, 0, stream>>>(counts, row_start, blocksums);
    k_scan2<<<1, 256, 0, stream>>>(blocksums);
    k_scan3<<<256, 256, 0, stream>>>(row_start, blocksums);
    k_fineB<<<NBUCK, 256, 0, stream>>>(cbuf, ccnt, row_start, csr);

    k_aggregate<<<N_NODES / 4, 256, 0, stream>>>(xs_bf, xd_bf, row_start, counts, csr,
                                                 att, bias, out);
}